// Round 3
// baseline (170.835 us; speedup 1.0000x reference)
//
#include <hip/hip_runtime.h>

// DigitCaps on MI355X, fp32 I/O. R14 = R13 votes body + fused finalization:
// the 20-block reduce_final kernel is DELETED. Votes blocks flush their LDS
// partials via device-scope integer atomics into tiny global accumulators
// (seg as int64 -- R3: winner-biased sums overflow int32; s as int32 --
// unbiased, sigma~8.8M, 238-sigma headroom), then take a ticket; the last
// ticket (1151) runs the final dc_new + output GEMV inline. No spin: ticket
// ==1151 implies all other blocks already fenced + incremented. Integer adds
// are exactly associative -> bit-identical totals to R9/R13 -> same absmax.
// A 5KB hipMemsetAsync at stream head zeroes done + accumulators (capture-
// safe; replaces the in-kernel done=0 which would race in fused form).
// Session evidence:
//   R2: fp32 atomicAdd = CAS loop -> native int atomics only.
//   R3: seg sums winner-biased -> int64 finals.
//   R5/R7/R8: VGPR cap below natural demand -> scratch spill (WRITE_SIZE).
//   R9: register W-slice + dc, replicated LDS atomics -> 99.4us.
//   R10 neutral, R11 regression, R13 (dc->SGPR + (256,4)) neutral:
//     votes-kernel perturbations barely move the total. Remaining
//     controllable cost: 2nd dispatch + partials round-trip (this round),
//     then harness floor (fill 43.5us @78% peak + restore + gaps).
//
// Sizes: B=128, J=4608, INPUT_D=8, D=8, M=4 -> N=18432 votes, C=10.
// Output = concat(output[128,10], digit_caps_new[10,8]).
// Math: output[b,c] = <(1/N) sum_n u[b,n], dc_new[c]> -> only s[b,:] needed.
//
// ws layout (BYTES):
//   [0,4)        done ticket counter
//   [64,832)     g_seg long long[96]  (col c*9+d; d==8 -> count)
//   [1024,5120)  g_s   int[1024]      (col b*8+d, scale 2^15)
//   memset span [0,5120).

#define J_POS 4608
#define SEGSTRIDE 97        // 97%32=1 -> replica r occupies bank r%32
#define NSEG 32
#define SSTRIDE 520
#define NSREP 8
#define NVOTES 18432.0f
#define DENOM  2359296.0f   // B*N
#define SEG_SCALE 32768.0f  // 2^15
#define INV_SEG_SCALE 3.0517578125e-5f

__global__ __launch_bounds__(256, 4) void votes_kernel(
    const float* __restrict__ x,   // [B, J, 8]
    const float* __restrict__ w,   // [J, 8, 32]
    const float* __restrict__ dc,  // [10, 8]
    long long* __restrict__ g_seg, // [96]
    int* __restrict__ g_s,         // [1024]
    int* __restrict__ done,
    float* __restrict__ out)       // [0,1280): output  [1280,1360): dc_new
{
    __shared__ int seg_lds[NSEG * SEGSTRIDE];   // 12.4 KB
    __shared__ int s_lds[NSREP * SSTRIDE];      // 16.6 KB
    __shared__ float sf[1024];                  // final-phase scratch
    __shared__ float dcn[80];
    __shared__ int lastflag;

    const int t  = threadIdx.x;
    const int jg = blockIdx.x >> 1;
    const int h  = blockIdx.x & 1;      // batch half
    const int j0 = jg * 8;

    for (int i = t; i < NSEG * SEGSTRIDE; i += 256) seg_lds[i] = 0;
    for (int i = t; i < NSREP * SSTRIDE; i += 256) s_lds[i] = 0;

    const int jj   = t >> 5;           // 0..7 : this thread's j
    const int m    = (t >> 3) & 3;     // 0..3 : this thread's vote column
    const int brow = t & 7;            // 0..7 : batch row within iter
    const int j = j0 + jj;

    // ---- W slice (8 i x 8 d for this (j,m)) -> 64 registers, loaded once
    float4 wra[8], wrb[8];
    {
        const float* wp = w + (size_t)j * 256 + m * 8;
        #pragma unroll
        for (int i = 0; i < 8; ++i) {
            wra[i] = *(const float4*)(wp + i * 32);
            wrb[i] = *(const float4*)(wp + i * 32 + 4);
        }
    }

    // ---- all of dc, forced wave-uniform (SGPR class via readfirstlane)
    float dcs[80];
    #pragma unroll
    for (int c = 0; c < 10; ++c) {
        const float4 a = *(const float4*)(dc + c * 8);
        const float4 b = *(const float4*)(dc + c * 8 + 4);
        dcs[c*8+0] = __uint_as_float(__builtin_amdgcn_readfirstlane(__float_as_uint(a.x)));
        dcs[c*8+1] = __uint_as_float(__builtin_amdgcn_readfirstlane(__float_as_uint(a.y)));
        dcs[c*8+2] = __uint_as_float(__builtin_amdgcn_readfirstlane(__float_as_uint(a.z)));
        dcs[c*8+3] = __uint_as_float(__builtin_amdgcn_readfirstlane(__float_as_uint(a.w)));
        dcs[c*8+4] = __uint_as_float(__builtin_amdgcn_readfirstlane(__float_as_uint(b.x)));
        dcs[c*8+5] = __uint_as_float(__builtin_amdgcn_readfirstlane(__float_as_uint(b.y)));
        dcs[c*8+6] = __uint_as_float(__builtin_amdgcn_readfirstlane(__float_as_uint(b.z)));
        dcs[c*8+7] = __uint_as_float(__builtin_amdgcn_readfirstlane(__float_as_uint(b.w)));
    }

    int* const segp = &seg_lds[((t >> 1) & (NSEG - 1)) * SEGSTRIDE];
    // lanes sharing one b in a wave = {jj&1, m} -> 8 distinct replicas: 1-way
    int* const sp = &s_lds[((t >> 3) & (NSREP - 1)) * SSTRIDE];

    __syncthreads();

    // ---- software-pipelined x loads (1-ahead) to hide HBM latency
    const float* xp0 = x + ((size_t)(h * 64 + brow) * J_POS + j) * 8;
    float4 nx0 = *(const float4*)xp0;
    float4 nx1 = *(const float4*)(xp0 + 4);

    #pragma unroll 1
    for (int it = 0; it < 8; ++it) {
        const int bl = it * 8 + brow;       // local b 0..63
        const float4 x0 = nx0, x1 = nx1;
        if (it < 7) {
            const float* xp = x + ((size_t)(h * 64 + bl + 8) * J_POS + j) * 8;
            nx0 = *(const float4*)xp;
            nx1 = *(const float4*)(xp + 4);
        }
        const float xf[8] = {x0.x,x0.y,x0.z,x0.w,x1.x,x1.y,x1.z,x1.w};

        // ---- one vote: u[8], all operands in registers
        float u[8] = {0,0,0,0,0,0,0,0};
        #pragma unroll
        for (int i = 0; i < 8; ++i) {
            const float xi = xf[i];
            u[0] += xi * wra[i].x; u[1] += xi * wra[i].y;
            u[2] += xi * wra[i].z; u[3] += xi * wra[i].w;
            u[4] += xi * wrb[i].x; u[5] += xi * wrb[i].y;
            u[6] += xi * wrb[i].z; u[7] += xi * wrb[i].w;
        }

        // ---- argmax over 10 caps (strict > = first max, jnp)
        float best = -3.402823466e38f;
        int bc = 0;
        #pragma unroll
        for (int c = 0; c < 10; ++c) {
            const float sim = u[0]*dcs[c*8+0] + u[1]*dcs[c*8+1]
                            + u[2]*dcs[c*8+2] + u[3]*dcs[c*8+3]
                            + u[4]*dcs[c*8+4] + u[5]*dcs[c*8+5]
                            + u[6]*dcs[c*8+6] + u[7]*dcs[c*8+7];
            if (sim > best) { best = sim; bc = c; }
        }

        // ---- fixed-point LDS atomics, fire-and-forget
        const int o = bc * 9;
        const int sb = bl * 8;
        #pragma unroll
        for (int d = 0; d < 8; ++d) {
            const int q = __float2int_rn(u[d] * SEG_SCALE);
            atomicAdd(&segp[o + d], q);
            atomicAdd(&sp[sb + d], q);
        }
        atomicAdd(&segp[o + 8], 1);
    }

    __syncthreads();

    // ---- flush partials: device-scope integer atomics into tiny globals.
    // seg as int64 (winner-biased, int32 would overflow at full-N totals);
    // s as int32 (unbiased, 238-sigma headroom). Fire-and-forget; hardware
    // drains outstanding ops before block retire.
    if (t < 90) {
        int v = 0;
        #pragma unroll
        for (int r = 0; r < NSEG; ++r) v += seg_lds[r * SEGSTRIDE + t];
        atomicAdd((unsigned long long*)&g_seg[t],
                  (unsigned long long)(long long)v);
    }
    #pragma unroll
    for (int e = t; e < 512; e += 256) {
        int v = 0;
        #pragma unroll
        for (int r = 0; r < NSREP; ++r) v += s_lds[r * SSTRIDE + e];
        atomicAdd(&g_s[h * 512 + e], v);
    }

    // ---- ticket protocol: release my atomics, take a ticket; last block
    // (ticket 1151) finalizes -- all 1151 others have already fenced.
    __threadfence();
    __syncthreads();
    if (t == 0) lastflag = (atomicAdd(done, 1) == 1151) ? 1 : 0;
    __syncthreads();
    if (!lastflag) return;
    __threadfence();   // acquire side

    // ---- final (one block): dc_new + output GEMV; agent-scope loads
    #pragma unroll
    for (int r = 0; r < 4; ++r) {
        const int i = r * 256 + t;
        const int v = __hip_atomic_load(&g_s[i], __ATOMIC_RELAXED,
                                        __HIP_MEMORY_SCOPE_AGENT);
        sf[i] = (float)v * INV_SEG_SCALE * (1.0f / NVOTES);
    }
    if (t < 80) {
        const int c = t >> 3, d = t & 7;
        const long long sv = __hip_atomic_load(&g_seg[c * 9 + d], __ATOMIC_RELAXED,
                                               __HIP_MEMORY_SCOPE_AGENT);
        const long long cv = __hip_atomic_load(&g_seg[c * 9 + 8], __ATOMIC_RELAXED,
                                               __HIP_MEMORY_SCOPE_AGENT);
        const float d0 = dc[t];
        const float nd = d0 + ((float)sv * INV_SEG_SCALE - (float)cv * d0) * (1.0f / DENOM);
        dcn[t] = nd;
        out[1280 + t] = nd;
    }
    __syncthreads();

    #pragma unroll
    for (int r = 0; r < 5; ++r) {
        const int idx = r * 256 + t;        // 0..1279
        const int b = idx / 10, c = idx - b * 10;
        float acc = 0.f;
        #pragma unroll
        for (int d = 0; d < 8; ++d) acc += sf[b * 8 + d] * dcn[c * 8 + d];
        out[idx] = acc;
    }
}

extern "C" void kernel_launch(void* const* d_in, const int* in_sizes, int n_in,
                              void* d_out, int out_size, void* d_ws, size_t ws_size,
                              hipStream_t stream) {
    const float* x  = (const float*)d_in[0];
    const float* w  = (const float*)d_in[1];
    const float* dc = (const float*)d_in[2];
    float* out = (float*)d_out;
    int*       done  = (int*)d_ws;
    long long* g_seg = (long long*)((char*)d_ws + 64);
    int*       g_s   = (int*)((char*)d_ws + 1024);

    // zero done + accumulators (workspace arrives poisoned); capture-safe
    hipMemsetAsync(d_ws, 0, 5120, stream);
    votes_kernel<<<1152, 256, 0, stream>>>(x, w, dc, g_seg, g_s, done, out);
}